// Round 1
// baseline (123.983 us; speedup 1.0000x reference)
//
#include <hip/hip_runtime.h>
#include <hip/hip_bf16.h>

#define NF 50
#define NP 1225          // NF*(NF-1)/2
#define ED 16
#define AS 16
#define NBATCH 8192
#define XPAD 20          // padded LDS row stride (floats): 16B-aligned, bank-spread
#define NTILES ((NP + 31) / 32)   // 39
#define WAVES 4

typedef __attribute__((ext_vector_type(8))) short short8;
typedef __attribute__((ext_vector_type(16))) float f32x16;

__device__ __forceinline__ unsigned short f2bf(float f) {
  unsigned int u = __builtin_bit_cast(unsigned int, f);
  u += 0x7fffu + ((u >> 16) & 1u);   // RNE
  return (unsigned short)(u >> 16);
}
__device__ __forceinline__ float bf2f(unsigned short h) {
  unsigned int u = ((unsigned int)h) << 16;
  return __builtin_bit_cast(float, u);
}

#if __has_builtin(__builtin_amdgcn_exp2f)
#define EXP2(x) __builtin_amdgcn_exp2f(x)
#else
#define EXP2(x) exp2f(x)
#endif

__global__ __launch_bounds__(256, 4) void afm_kernel(
    const float* __restrict__ x,
    const float* __restrict__ attn_W,
    const float* __restrict__ attn_b,
    const float* __restrict__ proj_W,
    const float* __restrict__ fc_W,
    const float* __restrict__ fc_b,
    float* __restrict__ out)
{
  __shared__ float xs[WAVES][NF][XPAD];
  __shared__ unsigned int pair_off[NP];   // packed byte offsets: i*80 | (j*80)<<16

  const int tid = threadIdx.x;
  const int w = tid >> 6;          // wave id = which batch of the 4
  const int lane = tid & 63;
  const int batch = blockIdx.x * WAVES + w;
  const int g2 = lane >> 5;        // k-group (d-half) 0/1
  const int nl = lane & 31;        // pair slot within tile / A-row
  const int d0 = g2 * 8;

  // ---- pair table (block-wide, once) ----
  for (int p = tid; p < NP; p += 256) {
    int rem = p, i = 0, cnt = NF - 1;
    while (rem >= cnt) { rem -= cnt; --cnt; ++i; }
    int j = i + 1 + rem;
    pair_off[p] = (unsigned)(i * (XPAD * 4)) | ((unsigned)(j * (XPAD * 4)) << 16);
  }

  // ---- stage x[batch] into LDS (per wave, coalesced float4) ----
  const float* xb = x + (size_t)batch * (NF * ED);
  for (int f4 = lane; f4 < (NF * ED) / 4; f4 += 64) {
    float4 v = reinterpret_cast<const float4*>(xb)[f4];
    int idx = f4 * 4;
    *reinterpret_cast<float4*>(&xs[w][idx >> 4][idx & 15]) = v;
  }

  // ---- constant A-fragment: rows 0-15 = attn_W^T (bf16 hi), rows 16-31 = residual (lo) ----
  short8 afrag;
  #pragma unroll
  for (int e = 0; e < 8; ++e) {
    int d = d0 + e;
    if (nl < AS) {
      afrag[e] = (short)f2bf(attn_W[d * AS + nl]);
    } else {
      float wv = attn_W[d * AS + (nl - 16)];
      unsigned short hi = f2bf(wv);
      afrag[e] = (short)f2bf(wv - bf2f(hi));
    }
  }

  // ---- C-fragment carries attn_b (rows 0-15), 0 for residual rows; per-lane projW ----
  f32x16 cbias;
  float pw[8];
  #pragma unroll
  for (int r = 0; r < 8; ++r) {
    int arow = (r & 3) + 8 * (r >> 2) + 4 * g2;   // D-layout row for reg r
    cbias[r] = attn_b[arow];
    cbias[r + 8] = 0.0f;
    pw[r] = proj_W[arow];
  }
  float fcw[8];
  #pragma unroll
  for (int e = 0; e < 8; ++e) fcw[e] = fc_W[d0 + e];

  __syncthreads();

  const char* xwbase = (const char*)(&xs[w][0][0]);
  const float L2E = 1.4426950408889634f;
  float m = -1e30f, se = 0.0f, seg = 0.0f;

  for (int t = 0; t < NTILES; ++t) {
    int p = t * 32 + nl;
    int pc = p < NP ? p : NP - 1;
    unsigned int ij = pair_off[pc];
    const float* xi = (const float*)(xwbase + (ij & 0xffffu));
    const float* xj = (const float*)(xwbase + (ij >> 16));
    float4 a0 = *(const float4*)(xi + d0);
    float4 a1 = *(const float4*)(xi + d0 + 4);
    float4 b0 = *(const float4*)(xj + d0);
    float4 b1 = *(const float4*)(xj + d0 + 4);
    float ip0 = a0.x * b0.x, ip1 = a0.y * b0.y, ip2 = a0.z * b0.z, ip3 = a0.w * b0.w;
    float ip4 = a1.x * b1.x, ip5 = a1.y * b1.y, ip6 = a1.z * b1.z, ip7 = a1.w * b1.w;

    short8 bfrag;
    bfrag[0] = (short)f2bf(ip0); bfrag[1] = (short)f2bf(ip1);
    bfrag[2] = (short)f2bf(ip2); bfrag[3] = (short)f2bf(ip3);
    bfrag[4] = (short)f2bf(ip4); bfrag[5] = (short)f2bf(ip5);
    bfrag[6] = (short)f2bf(ip6); bfrag[7] = (short)f2bf(ip7);

    // D[a][p] (rows 0-15) + D[a+16][p] (residual) ; bias pre-added via C
    f32x16 dacc = __builtin_amdgcn_mfma_f32_32x32x16_bf16(afrag, bfrag, cbias, 0, 0, 0);

    float sh = 0.0f;
    #pragma unroll
    for (int r = 0; r < 8; ++r) {
      float h = dacc[r] + dacc[r + 8];
      h = fmaxf(h, 0.0f);
      sh = fmaf(h, pw[r], sh);
    }
    float gh = 0.0f;
    gh = fmaf(ip0, fcw[0], gh); gh = fmaf(ip1, fcw[1], gh);
    gh = fmaf(ip2, fcw[2], gh); gh = fmaf(ip3, fcw[3], gh);
    gh = fmaf(ip4, fcw[4], gh); gh = fmaf(ip5, fcw[5], gh);
    gh = fmaf(ip6, fcw[6], gh); gh = fmaf(ip7, fcw[7], gh);

    float s = sh + __shfl_xor(sh, 32, 64);   // combine the two 8-row halves
    float g = gh + __shfl_xor(gh, 32, 64);   // combine the two d-halves (fp32 exact path)

    float svalid = (p < NP) ? s : -1e30f;
    float mnew = fmaxf(m, svalid);
    float e1 = EXP2((svalid - mnew) * L2E);
    float fr = EXP2((m - mnew) * L2E);
    se = se * fr + e1;
    seg = fmaf(e1, g, seg * fr);
    m = mnew;
  }

  // ---- merge 64 lane-slot online-softmax states (duplication cancels in the ratio) ----
  #pragma unroll
  for (int off = 1; off < 64; off <<= 1) {
    float m2 = __shfl_xor(m, off, 64);
    float se2 = __shfl_xor(se, off, 64);
    float sg2 = __shfl_xor(seg, off, 64);
    float mm = fmaxf(m, m2);
    float fa = EXP2((m - mm) * L2E);
    float fb = EXP2((m2 - mm) * L2E);
    se = se * fa + se2 * fb;
    seg = seg * fa + sg2 * fb;
    m = mm;
  }

  if (lane == 0) out[batch] = seg / se + fc_b[0];
}

extern "C" void kernel_launch(void* const* d_in, const int* in_sizes, int n_in,
                              void* d_out, int out_size, void* d_ws, size_t ws_size,
                              hipStream_t stream) {
  const float* x      = (const float*)d_in[0];
  const float* attn_W = (const float*)d_in[1];
  const float* attn_b = (const float*)d_in[2];
  const float* proj_W = (const float*)d_in[3];
  // d_in[4] = proj_b: unused — uniform score shift is softmax-invariant
  const float* fc_W   = (const float*)d_in[5];
  const float* fc_b   = (const float*)d_in[6];
  float* out = (float*)d_out;

  dim3 grid(NBATCH / WAVES);
  dim3 block(256);
  afm_kernel<<<grid, block, 0, stream>>>(x, attn_W, attn_b, proj_W, fc_W, fc_b, out);
}

// Round 4
// 109.147 us; speedup vs baseline: 1.1359x; 1.1359x over previous
//
#include <hip/hip_runtime.h>
#include <hip/hip_bf16.h>

#define NF 50
#define NP 1225          // NF*(NF-1)/2
#define ED 16
#define AS 16
#define NBATCH 8192
#define XPAD 20          // padded LDS row stride (floats): 16B-aligned, bank-spread
#define WAVES 4
#define NFULL 38         // full 32-pair tiles; tail has 9 pairs

typedef __attribute__((ext_vector_type(8))) short short8;
typedef __attribute__((ext_vector_type(16))) float f32x16;
typedef __attribute__((ext_vector_type(4))) unsigned int uint4v;

__device__ __forceinline__ unsigned cvt_pk_bf16(float lo, float hi) {
  unsigned r;
  asm("v_cvt_pk_bf16_f32 %0, %1, %2" : "=v"(r) : "v"(lo), "v"(hi));
  return r;
}
__device__ __forceinline__ float bf_round(float v) {   // f32 -> bf16(RNE) -> f32
  return __builtin_bit_cast(float, cvt_pk_bf16(v, v) << 16);
}

#if __has_builtin(__builtin_amdgcn_exp2f)
#define EXP2(x) __builtin_amdgcn_exp2f(x)
#else
#define EXP2(x) exp2f(x)
#endif

__global__ __launch_bounds__(256, 4) void afm_kernel(
    const float* __restrict__ x,
    const float* __restrict__ attn_W,
    const float* __restrict__ attn_b,
    const float* __restrict__ proj_W,
    const float* __restrict__ fc_W,
    const float* __restrict__ fc_b,
    float* __restrict__ out)
{
  __shared__ __align__(16) float xs[WAVES][NF][XPAD];   // 16000 B
  __shared__ unsigned pair_off[NP];                     // i*80 | (j*80)<<16 (byte offsets)

  const int tid = threadIdx.x;
  const int w = tid >> 6;
  const int lane = tid & 63;
  const int batch = blockIdx.x * WAVES + w;
  const int g2 = lane >> 5;        // d-half (K-group)
  const int nl = lane & 31;        // pair slot / A-row

  // ---- pair table, closed form (once per block) ----
  for (int p = tid; p < NP; p += 256) {
    float sq = sqrtf((float)(9801 - 8 * p));
    int i = (int)((99.0f - sq) * 0.5f);
    while ((i + 1) * (99 - (i + 1)) / 2 <= p) ++i;
    while (i * (99 - i) / 2 > p) --i;
    int j = i + 1 + (p - i * (99 - i) / 2);
    pair_off[p] = (unsigned)(i * (XPAD * 4)) | ((unsigned)(j * (XPAD * 4)) << 16);
  }

  // ---- stage x[batch] into LDS (per wave, coalesced float4) ----
  const float* xb = x + (size_t)batch * (NF * ED);
  for (int f4 = lane; f4 < (NF * ED) / 4; f4 += 64) {
    float4 v = reinterpret_cast<const float4*>(xb)[f4];
    int fi = f4 * 4;
    *reinterpret_cast<float4*>(&xs[w][fi >> 4][fi & 15]) = v;
  }

  // ---- A fragment (bf16): rows 0-15 = attn_W^T (hi), rows 16-31 = residual (lo) ----
  // R1-proven numerics: absmax 9.8e-4.
  float av[8];
  #pragma unroll
  for (int e = 0; e < 8; ++e) {
    int d = g2 * 8 + e;
    if (nl < AS) {
      av[e] = attn_W[d * AS + nl];
    } else {
      float wv = attn_W[d * AS + (nl - 16)];
      av[e] = wv - bf_round(wv);
    }
  }
  uint4v aw;
  aw[0] = cvt_pk_bf16(av[0], av[1]);
  aw[1] = cvt_pk_bf16(av[2], av[3]);
  aw[2] = cvt_pk_bf16(av[4], av[5]);
  aw[3] = cvt_pk_bf16(av[6], av[7]);
  const short8 afrag = __builtin_bit_cast(short8, aw);

  // ---- C carries attn_b on rows 0-15, zero on residual rows; pw pre-scaled by log2(e) ----
  f32x16 cbias;
  float pwl[8];
  #pragma unroll
  for (int r = 0; r < 8; ++r) {
    int arow = (r & 3) + 8 * (r >> 2) + 4 * g2;   // D-layout row for reg r (r<8)
    cbias[r] = attn_b[arow];
    cbias[r + 8] = 0.0f;                          // residual rows: no bias
    pwl[r] = proj_W[arow] * 1.4426950408889634f;
  }
  // g path stays fp32-exact: per-lane fc_W slice for this d-half
  float fcw[8];
  #pragma unroll
  for (int e = 0; e < 8; ++e) fcw[e] = fc_W[g2 * 8 + e];

  __syncthreads();

  const char* xwb = (const char*)(&xs[w][0][0]) + g2 * 32;   // fold d-half into base
  float se = 0.0f, seg = 0.0f;

  // tile body: s via MFMA (hi+lo rows), g via fp32 FMAs (own half only)
  auto tile = [&](unsigned ij, float& e1_out, float& gh_out) {
    const char* xi = xwb + (ij & 0xffffu);
    const char* xj = xwb + (ij >> 16);
    float4 a0 = *(const float4*)(xi);
    float4 a1 = *(const float4*)(xi + 16);
    float4 b0 = *(const float4*)(xj);
    float4 b1 = *(const float4*)(xj + 16);
    float ip0 = a0.x * b0.x, ip1 = a0.y * b0.y, ip2 = a0.z * b0.z, ip3 = a0.w * b0.w;
    float ip4 = a1.x * b1.x, ip5 = a1.y * b1.y, ip6 = a1.z * b1.z, ip7 = a1.w * b1.w;

    uint4v bw;
    bw[0] = cvt_pk_bf16(ip0, ip1);
    bw[1] = cvt_pk_bf16(ip2, ip3);
    bw[2] = cvt_pk_bf16(ip4, ip5);
    bw[3] = cvt_pk_bf16(ip6, ip7);
    short8 bfrag = __builtin_bit_cast(short8, bw);

    f32x16 dacc = __builtin_amdgcn_mfma_f32_32x32x16_bf16(afrag, bfrag, cbias, 0, 0, 0);

    float sh = 0.0f;
    #pragma unroll
    for (int r = 0; r < 8; ++r)
      sh = fmaf(fmaxf(dacc[r] + dacc[r + 8], 0.0f), pwl[r], sh);   // hi+lo, relu, *pw

    float gh = 0.0f;
    gh = fmaf(ip0, fcw[0], gh); gh = fmaf(ip1, fcw[1], gh);
    gh = fmaf(ip2, fcw[2], gh); gh = fmaf(ip3, fcw[3], gh);
    gh = fmaf(ip4, fcw[4], gh); gh = fmaf(ip5, fcw[5], gh);
    gh = fmaf(ip6, fcw[6], gh); gh = fmaf(ip7, fcw[7], gh);

    // s cross-half combine: duplicated-operand permlane32_swap -> both lanes get S_lo+S_hi
    float c = sh;
    asm("v_permlane32_swap_b32 %0, %1" : "+v"(sh), "+v"(c));
    e1_out = EXP2(sh + c);     // |s| small: no running max needed (exact in ratio)
    gh_out = gh;               // half-partial; totals via final 64-lane reduce
  };

  #pragma unroll 2
  for (int t = 0; t < NFULL; ++t) {
    float e1, gh;
    tile(pair_off[t * 32 + nl], e1, gh);
    se += e1;                      // duplicated 2x across halves (cancels via final 2x)
    seg = fmaf(e1, gh, seg);       // half-partials -> summed once by final reduce
  }
  { // tail tile: pairs 1216..1224 (9 valid)
    int idx = NFULL * 32 + nl;
    bool valid = idx < NP;
    float e1, gh;
    tile(pair_off[valid ? idx : NP - 1], e1, gh);
    e1 = valid ? e1 : 0.0f;
    se += e1;
    seg = fmaf(e1, gh, seg);
  }

  // ---- final reduce over 64 lanes ----
  #pragma unroll
  for (int off = 1; off < 64; off <<= 1) {
    se += __shfl_xor(se, off, 64);
    seg += __shfl_xor(seg, off, 64);
  }
  if (lane == 0) out[batch] = 2.0f * seg / se + fc_b[0];
}

extern "C" void kernel_launch(void* const* d_in, const int* in_sizes, int n_in,
                              void* d_out, int out_size, void* d_ws, size_t ws_size,
                              hipStream_t stream) {
  const float* x      = (const float*)d_in[0];
  const float* attn_W = (const float*)d_in[1];
  const float* attn_b = (const float*)d_in[2];
  const float* proj_W = (const float*)d_in[3];
  // d_in[4] = proj_b: unused — uniform score shift is softmax-invariant
  const float* fc_W   = (const float*)d_in[5];
  const float* fc_b   = (const float*)d_in[6];
  float* out = (float*)d_out;

  dim3 grid(NBATCH / WAVES);
  dim3 block(256);
  afm_kernel<<<grid, block, 0, stream>>>(x, attn_W, attn_b, proj_W, fc_W, fc_b, out);
}